// Round 1
// baseline (262.467 us; speedup 1.0000x reference)
//
#include <hip/hip_runtime.h>
#include <hip/hip_bf16.h>
#include <cstdint>

#define TB 8
#define TN 1024
#define TC 768
#define TH 12
#define THD 64
#define TM (TB*TN)          // 8192 rows
#define TNQKV (3*TC)        // 2304
#define ASCALE 0.125f       // HD^-0.5

typedef __attribute__((ext_vector_type(8))) short s16x8;
typedef __attribute__((ext_vector_type(4))) float f32x4;

__device__ __forceinline__ unsigned short f2bf(float f) {
    union { float f; unsigned int u; } v; v.f = f;
    unsigned int u = v.u;
    return (unsigned short)((u + 0x7FFFu + ((u >> 16) & 1u)) >> 16);
}

__device__ __forceinline__ void gload_lds16(const unsigned short* g, unsigned short* l) {
    __builtin_amdgcn_global_load_lds(
        (const __attribute__((address_space(1))) unsigned int*)g,
        (__attribute__((address_space(3))) unsigned int*)l,
        16, 0, 0);
}

// ---------------- f32 -> bf16 conversion (vectorized, memory-bound) ----------
__global__ __launch_bounds__(256) void cvt_kernel(const float* __restrict__ in,
                                                  unsigned short* __restrict__ out,
                                                  int n8) {
    int i = blockIdx.x * blockDim.x + threadIdx.x;
    if (i >= n8) return;
    f32x4 a = *(const f32x4*)(in + (size_t)i * 8);
    f32x4 b = *(const f32x4*)(in + (size_t)i * 8 + 4);
    s16x8 r;
    #pragma unroll
    for (int e = 0; e < 4; e++) r[e] = (short)f2bf(a[e]);
    #pragma unroll
    for (int e = 0; e < 4; e++) r[4 + e] = (short)f2bf(b[e]);
    *(s16x8*)(out + (size_t)i * 8) = r;
}

// ---------------- bf16 GEMM, C = A * B^T (+bias). m97-style 128x128 tile -----
// A: [M][K] bf16 row-major; Bm: [N][K] bf16 row-major (i.e. B^T, K-contig)
template<bool BIAS, bool OBF16>
__global__ __launch_bounds__(256) void gemm_bt(
    const unsigned short* __restrict__ A,
    const unsigned short* __restrict__ Bm,
    void* __restrict__ Cout,
    const float* __restrict__ bias,
    int M, int Nn, int K)
{
    __shared__ unsigned short As[128 * 32];
    __shared__ unsigned short Bs[128 * 32];
    const int t = threadIdx.x;
    const int w = t >> 6, l = t & 63;
    const int lr = l & 15, lh = l >> 4;
    const int wm = w >> 1, wn = w & 1;     // 2x2 wave grid, 64x64 out per wave
    const int bm = blockIdx.x, bn = blockIdx.y;

    f32x4 acc[4][4] = {};

    const unsigned short* Ab = A + (size_t)bm * 128 * K;
    const unsigned short* Bb = Bm + (size_t)bn * 128 * K;

    for (int kt = 0; kt < K; kt += 32) {
        __syncthreads();
        {
            const int c0 = t, c1 = t + 256;
            gload_lds16(Ab + (size_t)(c0 >> 2) * K + kt + (c0 & 3) * 8, As + c0 * 8);
            gload_lds16(Ab + (size_t)(c1 >> 2) * K + kt + (c1 & 3) * 8, As + c1 * 8);
            gload_lds16(Bb + (size_t)(c0 >> 2) * K + kt + (c0 & 3) * 8, Bs + c0 * 8);
            gload_lds16(Bb + (size_t)(c1 >> 2) * K + kt + (c1 & 3) * 8, Bs + c1 * 8);
        }
        __syncthreads();
        s16x8 af[4], bfr[4];
        #pragma unroll
        for (int mi = 0; mi < 4; mi++)
            af[mi] = *(const s16x8*)(As + (wm * 64 + mi * 16 + lr) * 32 + lh * 8);
        #pragma unroll
        for (int ni = 0; ni < 4; ni++)
            bfr[ni] = *(const s16x8*)(Bs + (wn * 64 + ni * 16 + lr) * 32 + lh * 8);
        #pragma unroll
        for (int mi = 0; mi < 4; mi++)
            #pragma unroll
            for (int ni = 0; ni < 4; ni++)
                acc[mi][ni] = __builtin_amdgcn_mfma_f32_16x16x32_bf16(
                    af[mi], bfr[ni], acc[mi][ni], 0, 0, 0);
    }

    const int r0 = bm * 128 + wm * 64;
    const int c0 = bn * 128 + wn * 64;
    if constexpr (OBF16) {
        unsigned short* O = (unsigned short*)Cout;
        #pragma unroll
        for (int mi = 0; mi < 4; mi++)
            #pragma unroll
            for (int ni = 0; ni < 4; ni++)
                #pragma unroll
                for (int i = 0; i < 4; i++)
                    O[(size_t)(r0 + mi * 16 + lh * 4 + i) * Nn + c0 + ni * 16 + lr] =
                        f2bf(acc[mi][ni][i]);
    } else {
        float* O = (float*)Cout;
        #pragma unroll
        for (int mi = 0; mi < 4; mi++)
            #pragma unroll
            for (int ni = 0; ni < 4; ni++)
                #pragma unroll
                for (int i = 0; i < 4; i++) {
                    int cc = c0 + ni * 16 + lr;
                    float v = acc[mi][ni][i];
                    if constexpr (BIAS) v += bias[cc];
                    O[(size_t)(r0 + mi * 16 + lh * 4 + i) * Nn + cc] = v;
                }
    }
}

// ---------------- V transpose: vt[bh][d][k] = V[b,h,k,d] ---------------------
__global__ __launch_bounds__(256) void transpose_v(
    const unsigned short* __restrict__ qkv, unsigned short* __restrict__ vt)
{
    __shared__ unsigned short tile[64][72];   // +8 pad, rows 144B (16B aligned)
    const int kt = blockIdx.x, bh = blockIdx.y;
    const int b = bh / TH, h = bh % TH;
    const int t = threadIdx.x;
    const unsigned short* src = qkv + (size_t)(b * TN + kt * 64) * TNQKV + 2 * TC + h * THD;
    #pragma unroll
    for (int c = t; c < 512; c += 256) {
        int k = c >> 3, d8 = c & 7;
        *(s16x8*)&tile[k][d8 * 8] = *(const s16x8*)(src + (size_t)k * TNQKV + d8 * 8);
    }
    __syncthreads();
    unsigned short* dst = vt + (size_t)bh * THD * TN + kt * 64;
    #pragma unroll
    for (int c = t; c < 512; c += 256) {
        int d = c >> 3, k8 = c & 7;
        s16x8 v;
        #pragma unroll
        for (int e = 0; e < 8; e++) v[e] = tile[k8 * 8 + e][d];
        *(s16x8*)(dst + (size_t)d * TN + k8 * 8) = v;
    }
}

// ---------------- Flash attention: 1 block per (qtile, b*h) ------------------
// 4 waves x 16 q-rows = 64-row Q tile; KVBLK=32; online softmax.
__global__ __launch_bounds__(256) void attn_kernel(
    const unsigned short* __restrict__ qkv,
    const unsigned short* __restrict__ vt,
    unsigned short* __restrict__ out)     // [8192][768] bf16
{
    const int qt = blockIdx.x;            // 0..15
    const int bh = blockIdx.y;            // 0..95
    const int b = bh / TH, h = bh % TH;
    const int t = threadIdx.x, w = t >> 6, l = t & 63;
    const int lr = l & 15, lh = l >> 4;
    const int qbase = qt * 64 + w * 16;

    __shared__ unsigned short plds[4][16 * 40];  // per-wave P tile, stride 40 halfs

    // Q fragments (A operand): lane holds Q[qbase+lr][kh*32 + lh*8 .. +8]
    const unsigned short* qptr = qkv + (size_t)(b * TN + qbase + lr) * TNQKV + h * THD;
    s16x8 aq0 = *(const s16x8*)(qptr + lh * 8);
    s16x8 aq1 = *(const s16x8*)(qptr + 32 + lh * 8);

    f32x4 o[4] = {};          // out acc: row=lh*4+i, col=nd*16+lr (d)
    float mrow[4], lrow[4];
    #pragma unroll
    for (int i = 0; i < 4; i++) { mrow[i] = -1e30f; lrow[i] = 0.f; }

    const unsigned short* kbase = qkv + (size_t)(b * TN) * TNQKV + TC + h * THD;
    const unsigned short* vtb = vt + (size_t)bh * THD * TN;

    for (int kt = 0; kt < TN; kt += 32) {
        // --- S = Q K^T for 16q x 32k ---
        f32x4 s[2];
        #pragma unroll
        for (int nc = 0; nc < 2; nc++) {
            const unsigned short* kp = kbase + (size_t)(kt + nc * 16 + lr) * TNQKV;
            s16x8 bk0 = *(const s16x8*)(kp + lh * 8);
            s16x8 bk1 = *(const s16x8*)(kp + 32 + lh * 8);
            f32x4 z = {0.f, 0.f, 0.f, 0.f};
            z = __builtin_amdgcn_mfma_f32_16x16x32_bf16(aq0, bk0, z, 0, 0, 0);
            z = __builtin_amdgcn_mfma_f32_16x16x32_bf16(aq1, bk1, z, 0, 0, 0);
            s[nc] = z;
        }
        // --- online softmax (rows = lh*4+i, reduce across 16 lanes lr) ---
        float pm[2][4];
        #pragma unroll
        for (int nc = 0; nc < 2; nc++)
            #pragma unroll
            for (int i = 0; i < 4; i++) pm[nc][i] = s[nc][i] * ASCALE;
        #pragma unroll
        for (int i = 0; i < 4; i++) {
            float mx = fmaxf(pm[0][i], pm[1][i]);
            #pragma unroll
            for (int off = 1; off < 16; off <<= 1) mx = fmaxf(mx, __shfl_xor(mx, off, 64));
            float newm = fmaxf(mrow[i], mx);
            float corr = __expf(mrow[i] - newm);
            float ps = 0.f;
            #pragma unroll
            for (int nc = 0; nc < 2; nc++) {
                float p = __expf(pm[nc][i] - newm);
                pm[nc][i] = p; ps += p;
            }
            #pragma unroll
            for (int off = 1; off < 16; off <<= 1) ps += __shfl_xor(ps, off, 64);
            lrow[i] = lrow[i] * corr + ps;
            mrow[i] = newm;
            #pragma unroll
            for (int nd = 0; nd < 4; nd++) o[nd][i] *= corr;
        }
        // --- P -> LDS (bf16), refragment as A operand ---
        unsigned short* pw = plds[w];
        #pragma unroll
        for (int nc = 0; nc < 2; nc++)
            #pragma unroll
            for (int i = 0; i < 4; i++)
                pw[(lh * 4 + i) * 40 + nc * 16 + lr] = f2bf(pm[nc][i]);
        s16x8 ap = *(const s16x8*)(plds[w] + lr * 40 + lh * 8);
        // --- O += P V  (B operand from Vt, K-contig) ---
        #pragma unroll
        for (int nd = 0; nd < 4; nd++) {
            s16x8 bv = *(const s16x8*)(vtb + (size_t)(nd * 16 + lr) * TN + kt + lh * 8);
            o[nd] = __builtin_amdgcn_mfma_f32_16x16x32_bf16(ap, bv, o[nd], 0, 0, 0);
        }
    }

    // epilogue: normalize by lrow, write bf16 to [b*N+q][h*64+d]
    unsigned short* op = out + (size_t)(b * TN + qbase) * TC + h * THD;
    #pragma unroll
    for (int i = 0; i < 4; i++) {
        float inv = 1.f / lrow[i];
        #pragma unroll
        for (int nd = 0; nd < 4; nd++)
            op[(size_t)(lh * 4 + i) * TC + nd * 16 + lr] = f2bf(o[nd][i] * inv);
    }
}

extern "C" void kernel_launch(void* const* d_in, const int* in_sizes, int n_in,
                              void* d_out, int out_size, void* d_ws, size_t ws_size,
                              hipStream_t stream) {
    const float* x      = (const float*)d_in[0];
    const float* w_qkv  = (const float*)d_in[1];
    const float* w_proj = (const float*)d_in[2];
    const float* b_proj = (const float*)d_in[3];
    float* out = (float*)d_out;

    // workspace layout (bf16 = unsigned short), ~80 MB total
    unsigned short* xb   = (unsigned short*)d_ws;
    unsigned short* wqb  = xb   + (size_t)TM * TC;        // 2304x768
    unsigned short* wpb  = wqb  + (size_t)TNQKV * TC;     // 768x768
    unsigned short* qkvb = wpb  + (size_t)TC * TC;        // 8192x2304
    unsigned short* vtb  = qkvb + (size_t)TM * TNQKV;     // 96x64x1024
    unsigned short* aob  = vtb  + (size_t)TB * TH * THD * TN; // 8192x768

    int n8;
    n8 = TM * TC / 8;
    cvt_kernel<<<(n8 + 255) / 256, 256, 0, stream>>>(x, xb, n8);
    n8 = TNQKV * TC / 8;
    cvt_kernel<<<(n8 + 255) / 256, 256, 0, stream>>>(w_qkv, wqb, n8);
    n8 = TC * TC / 8;
    cvt_kernel<<<(n8 + 255) / 256, 256, 0, stream>>>(w_proj, wpb, n8);

    gemm_bt<false, true><<<dim3(TM / 128, TNQKV / 128), 256, 0, stream>>>(
        xb, wqb, (void*)qkvb, nullptr, TM, TNQKV, TC);

    transpose_v<<<dim3(TN / 64, TB * TH), 256, 0, stream>>>(qkvb, vtb);

    attn_kernel<<<dim3(TN / 64, TB * TH), 256, 0, stream>>>(qkvb, vtb, aob);

    gemm_bt<true, false><<<dim3(TM / 128, TC / 128), 256, 0, stream>>>(
        aob, wpb, (void*)out, b_proj, TM, TC, TC);
}

// Round 2
// 261.249 us; speedup vs baseline: 1.0047x; 1.0047x over previous
//
#include <hip/hip_runtime.h>
#include <hip/hip_bf16.h>
#include <cstdint>

#define TB 8
#define TN 1024
#define TC 768
#define TH 12
#define THD 64
#define TM (TB*TN)          // 8192 rows
#define TNQKV (3*TC)        // 2304
// SCALE * log2(e) = 0.125 * 1.4426950408889634
#define QSCALE_LOG2E 0.18033688011112042f

typedef __attribute__((ext_vector_type(8))) short s16x8;
typedef __attribute__((ext_vector_type(4))) short s16x4;
typedef __attribute__((ext_vector_type(4))) float f32x4;

__device__ __forceinline__ unsigned short f2bf(float f) {
    union { float f; unsigned int u; } v; v.f = f;
    unsigned int u = v.u;
    return (unsigned short)((u + 0x7FFFu + ((u >> 16) & 1u)) >> 16);
}

__device__ __forceinline__ float bf2f(unsigned short h) {
    union { float f; unsigned int u; } v; v.u = ((unsigned int)h) << 16;
    return v.f;
}

__device__ __forceinline__ void gload_lds16(const unsigned short* g, unsigned short* l) {
    __builtin_amdgcn_global_load_lds(
        (const __attribute__((address_space(1))) unsigned int*)g,
        (__attribute__((address_space(3))) unsigned int*)l,
        16, 0, 0);
}

// ---------------- f32 -> bf16 conversion (vectorized, memory-bound) ----------
__global__ __launch_bounds__(256) void cvt_kernel(const float* __restrict__ in,
                                                  unsigned short* __restrict__ out,
                                                  int n8) {
    int i = blockIdx.x * blockDim.x + threadIdx.x;
    if (i >= n8) return;
    f32x4 a = *(const f32x4*)(in + (size_t)i * 8);
    f32x4 b = *(const f32x4*)(in + (size_t)i * 8 + 4);
    s16x8 r;
    #pragma unroll
    for (int e = 0; e < 4; e++) r[e] = (short)f2bf(a[e]);
    #pragma unroll
    for (int e = 0; e < 4; e++) r[4 + e] = (short)f2bf(b[e]);
    *(s16x8*)(out + (size_t)i * 8) = r;
}

// ---------------- bf16 GEMM, C = A * B^T (+bias). m97-style 128x128 tile -----
template<bool BIAS, bool OBF16>
__global__ __launch_bounds__(256) void gemm_bt(
    const unsigned short* __restrict__ A,
    const unsigned short* __restrict__ Bm,
    void* __restrict__ Cout,
    const float* __restrict__ bias,
    int M, int Nn, int K)
{
    __shared__ unsigned short As[128 * 32];
    __shared__ unsigned short Bs[128 * 32];
    const int t = threadIdx.x;
    const int w = t >> 6, l = t & 63;
    const int lr = l & 15, lh = l >> 4;
    const int wm = w >> 1, wn = w & 1;     // 2x2 wave grid, 64x64 out per wave
    const int bm = blockIdx.x, bn = blockIdx.y;

    f32x4 acc[4][4] = {};

    const unsigned short* Ab = A + (size_t)bm * 128 * K;
    const unsigned short* Bb = Bm + (size_t)bn * 128 * K;

    for (int kt = 0; kt < K; kt += 32) {
        __syncthreads();
        {
            const int c0 = t, c1 = t + 256;
            gload_lds16(Ab + (size_t)(c0 >> 2) * K + kt + (c0 & 3) * 8, As + c0 * 8);
            gload_lds16(Ab + (size_t)(c1 >> 2) * K + kt + (c1 & 3) * 8, As + c1 * 8);
            gload_lds16(Bb + (size_t)(c0 >> 2) * K + kt + (c0 & 3) * 8, Bs + c0 * 8);
            gload_lds16(Bb + (size_t)(c1 >> 2) * K + kt + (c1 & 3) * 8, Bs + c1 * 8);
        }
        __syncthreads();
        s16x8 af[4], bfr[4];
        #pragma unroll
        for (int mi = 0; mi < 4; mi++)
            af[mi] = *(const s16x8*)(As + (wm * 64 + mi * 16 + lr) * 32 + lh * 8);
        #pragma unroll
        for (int ni = 0; ni < 4; ni++)
            bfr[ni] = *(const s16x8*)(Bs + (wn * 64 + ni * 16 + lr) * 32 + lh * 8);
        #pragma unroll
        for (int mi = 0; mi < 4; mi++)
            #pragma unroll
            for (int ni = 0; ni < 4; ni++)
                acc[mi][ni] = __builtin_amdgcn_mfma_f32_16x16x32_bf16(
                    af[mi], bfr[ni], acc[mi][ni], 0, 0, 0);
    }

    const int r0 = bm * 128 + wm * 64;
    const int c0 = bn * 128 + wn * 64;
    if constexpr (OBF16) {
        unsigned short* O = (unsigned short*)Cout;
        #pragma unroll
        for (int mi = 0; mi < 4; mi++)
            #pragma unroll
            for (int ni = 0; ni < 4; ni++)
                #pragma unroll
                for (int i = 0; i < 4; i++)
                    O[(size_t)(r0 + mi * 16 + lh * 4 + i) * Nn + c0 + ni * 16 + lr] =
                        f2bf(acc[mi][ni][i]);
    } else {
        float* O = (float*)Cout;
        #pragma unroll
        for (int mi = 0; mi < 4; mi++)
            #pragma unroll
            for (int ni = 0; ni < 4; ni++)
                #pragma unroll
                for (int i = 0; i < 4; i++) {
                    int cc = c0 + ni * 16 + lr;
                    float v = acc[mi][ni][i];
                    if constexpr (BIAS) v += bias[cc];
                    O[(size_t)(r0 + mi * 16 + lh * 4 + i) * Nn + cc] = v;
                }
    }
}

// ---------------- V transpose: vt[bh][d][k] = V[b,h,k,d] ---------------------
__global__ __launch_bounds__(256) void transpose_v(
    const unsigned short* __restrict__ qkv, unsigned short* __restrict__ vt)
{
    __shared__ unsigned short tile[64][72];   // +8 pad
    const int kt = blockIdx.x, bh = blockIdx.y;
    const int b = bh / TH, h = bh % TH;
    const int t = threadIdx.x;
    const unsigned short* src = qkv + (size_t)(b * TN + kt * 64) * TNQKV + 2 * TC + h * THD;
    #pragma unroll
    for (int c = t; c < 512; c += 256) {
        int k = c >> 3, d8 = c & 7;
        *(s16x8*)&tile[k][d8 * 8] = *(const s16x8*)(src + (size_t)k * TNQKV + d8 * 8);
    }
    __syncthreads();
    unsigned short* dst = vt + (size_t)bh * THD * TN + kt * 64;
    #pragma unroll
    for (int c = t; c < 512; c += 256) {
        int d = c >> 3, k8 = c & 7;
        s16x8 v;
        #pragma unroll
        for (int e = 0; e < 8; e++) v[e] = tile[k8 * 8 + e][d];
        *(s16x8*)(dst + (size_t)d * TN + k8 * 8) = v;
    }
}

// ---------------- Flash attention, swapped-QK^T (S^T = K·Q^T) ----------------
// 4 waves x 16 q-rows = 64-row Q tile; KVBLK=64; lane owns one q-row (q=lr).
__global__ __launch_bounds__(256) void attn_kernel(
    const unsigned short* __restrict__ qkv,
    const unsigned short* __restrict__ vt,
    unsigned short* __restrict__ out)     // [8192][768] bf16
{
    const int qt = blockIdx.x;            // 0..15
    const int bh = blockIdx.y;            // 0..95
    const int b = bh / TH, h = bh % TH;
    const int t = threadIdx.x, w = t >> 6, l = t & 63;
    const int lr = l & 15, lh = l >> 4;
    const int qbase = qt * 64 + w * 16;

    __shared__ unsigned short plds[4][16 * 72];  // per-wave P^ tile [q][k], stride 72

    // Q as B-operand fragments, pre-scaled by SCALE*log2e (so P = exp2(S'-m))
    const unsigned short* qptr = qkv + (size_t)(b * TN + qbase + lr) * TNQKV + h * THD;
    s16x8 bq[2];
    #pragma unroll
    for (int cj = 0; cj < 2; cj++) {
        s16x8 raw = *(const s16x8*)(qptr + cj * 32 + lh * 8);
        #pragma unroll
        for (int e = 0; e < 8; e++)
            bq[cj][e] = (short)f2bf(bf2f((unsigned short)raw[e]) * QSCALE_LOG2E);
    }

    f32x4 o[4] = {};          // O^T acc: q=lr, d = nd*16 + lh*4 + i
    float m2 = -1e30f, lsum = 0.f;

    const unsigned short* kbase = qkv + (size_t)(b * TN) * TNQKV + TC + h * THD;
    const unsigned short* vtb = vt + (size_t)bh * THD * TN;
    unsigned short* pw = plds[w];

    for (int kt = 0; kt < TN; kt += 64) {
        // --- S^T = K Q^T for 64k x 16q: lane gets S'[q=lr][k=kk*16+lh*4+i] ---
        f32x4 s[4];
        #pragma unroll
        for (int kk = 0; kk < 4; kk++) {
            const unsigned short* kp = kbase + (size_t)(kt + kk * 16 + lr) * TNQKV;
            s16x8 ak0 = *(const s16x8*)(kp + lh * 8);
            s16x8 ak1 = *(const s16x8*)(kp + 32 + lh * 8);
            f32x4 z = {0.f, 0.f, 0.f, 0.f};
            z = __builtin_amdgcn_mfma_f32_16x16x32_bf16(ak0, bq[0], z, 0, 0, 0);
            z = __builtin_amdgcn_mfma_f32_16x16x32_bf16(ak1, bq[1], z, 0, 0, 0);
            s[kk] = z;
        }
        // --- online softmax in log2 domain; reduce: in-lane tree + 2 shuffles ---
        float v[16];
        #pragma unroll
        for (int kk = 0; kk < 4; kk++)
            #pragma unroll
            for (int i = 0; i < 4; i++) v[kk * 4 + i] = s[kk][i];
        #pragma unroll
        for (int st = 8; st >= 1; st >>= 1)
            #pragma unroll
            for (int j = 0; j < st; j++) v[j] = fmaxf(v[j], v[j + st]);
        float mx = v[0];
        mx = fmaxf(mx, __shfl_xor(mx, 16, 64));
        mx = fmaxf(mx, __shfl_xor(mx, 32, 64));
        float newm = fmaxf(m2, mx);
        float corr = __builtin_amdgcn_exp2f(m2 - newm);
        float a[16];
        #pragma unroll
        for (int kk = 0; kk < 4; kk++)
            #pragma unroll
            for (int i = 0; i < 4; i++) {
                float p = __builtin_amdgcn_exp2f(s[kk][i] - newm);
                s[kk][i] = p;
                a[kk * 4 + i] = p;
            }
        #pragma unroll
        for (int st = 8; st >= 1; st >>= 1)
            #pragma unroll
            for (int j = 0; j < st; j++) a[j] += a[j + st];
        float ps = a[0];
        ps += __shfl_xor(ps, 16, 64);
        ps += __shfl_xor(ps, 32, 64);
        lsum = lsum * corr + ps;
        m2 = newm;
        #pragma unroll
        for (int nd = 0; nd < 4; nd++)
            #pragma unroll
            for (int i = 0; i < 4; i++) o[nd][i] *= corr;

        // --- P^T -> LDS tile [q=lr][k], 8B packed writes ---
        #pragma unroll
        for (int kk = 0; kk < 4; kk++) {
            s16x4 pk;
            #pragma unroll
            for (int i = 0; i < 4; i++) pk[i] = (short)f2bf(s[kk][i]);
            *(s16x4*)(pw + lr * 72 + kk * 16 + lh * 4) = pk;
        }
        // --- O^T += Vt P^T (A = Vt rows d, B = P rows q) ---
        #pragma unroll
        for (int ktile = 0; ktile < 2; ktile++) {
            s16x8 bp = *(const s16x8*)(pw + lr * 72 + ktile * 32 + lh * 8);
            #pragma unroll
            for (int nd = 0; nd < 4; nd++) {
                s16x8 av = *(const s16x8*)(vtb + (size_t)(nd * 16 + lr) * TN + kt + ktile * 32 + lh * 8);
                o[nd] = __builtin_amdgcn_mfma_f32_16x16x32_bf16(av, bp, o[nd], 0, 0, 0);
            }
        }
    }

    // epilogue: lane owns q=lr; d = nd*16 + lh*4 + i -> 8B packed stores
    float inv = 1.f / lsum;
    unsigned short* op = out + (size_t)(b * TN + qbase + lr) * TC + h * THD;
    #pragma unroll
    for (int nd = 0; nd < 4; nd++) {
        s16x4 r;
        #pragma unroll
        for (int i = 0; i < 4; i++) r[i] = (short)f2bf(o[nd][i] * inv);
        *(s16x4*)(op + nd * 16 + lh * 4) = r;
    }
}

extern "C" void kernel_launch(void* const* d_in, const int* in_sizes, int n_in,
                              void* d_out, int out_size, void* d_ws, size_t ws_size,
                              hipStream_t stream) {
    const float* x      = (const float*)d_in[0];
    const float* w_qkv  = (const float*)d_in[1];
    const float* w_proj = (const float*)d_in[2];
    const float* b_proj = (const float*)d_in[3];
    float* out = (float*)d_out;

    unsigned short* xb   = (unsigned short*)d_ws;
    unsigned short* wqb  = xb   + (size_t)TM * TC;
    unsigned short* wpb  = wqb  + (size_t)TNQKV * TC;
    unsigned short* qkvb = wpb  + (size_t)TC * TC;
    unsigned short* vtb  = qkvb + (size_t)TM * TNQKV;
    unsigned short* aob  = vtb  + (size_t)TB * TH * THD * TN;

    int n8;
    n8 = TM * TC / 8;
    cvt_kernel<<<(n8 + 255) / 256, 256, 0, stream>>>(x, xb, n8);
    n8 = TNQKV * TC / 8;
    cvt_kernel<<<(n8 + 255) / 256, 256, 0, stream>>>(w_qkv, wqb, n8);
    n8 = TC * TC / 8;
    cvt_kernel<<<(n8 + 255) / 256, 256, 0, stream>>>(w_proj, wpb, n8);

    gemm_bt<false, true><<<dim3(TM / 128, TNQKV / 128), 256, 0, stream>>>(
        xb, wqb, (void*)qkvb, nullptr, TM, TNQKV, TC);

    transpose_v<<<dim3(TN / 64, TB * TH), 256, 0, stream>>>(qkvb, vtb);

    attn_kernel<<<dim3(TN / 64, TB * TH), 256, 0, stream>>>(qkvb, vtb, aob);

    gemm_bt<true, false><<<dim3(TM / 128, TC / 128), 256, 0, stream>>>(
        aob, wpb, (void*)out, b_proj, TM, TC, TC);
}